// Round 4
// baseline (92.697 us; speedup 1.0000x reference)
//
#include <hip/hip_runtime.h>
#include <hip/hip_bf16.h>

// Problem constants
#define BATCH 2
#define NPTS 2048
#define NCH 64
#define IMG 128
#define KTOP 8
#define BIGF 1e10f
#define CAP 128     // per-row candidate capacity (expected ~48, sigma ~7, seed fixed)
#define FPITCH 68   // feature row pitch in floats (68*4=272B, 16B-aligned, bank-spread)

// ---------------------------------------------------------------------------
// Single fused kernel: scan + gather-transpose + rasterize(top-8 z) + composite.
// Grid: B*IMG*2 = 512 blocks x 256 threads. Block = half image row (64 px).
//
// Phase 1: 256 threads y-band-filter all 2048 points into an LDS candidate
//          list (dy^2 <= r2 is conservative vs dx^2+dy^2 <= r2 since
//          fl(dx^2+dy^2) >= dy^2 for nonneg addends; bit-identical dy).
// Phase 2: stage the candidates' 64-channel feature rows src[b,:,p] into LDS
//          (transposed on the fly; scattered 4B L2-hit reads, src is 2 MB and
//          L2-resident; writes are conflict-free).
// Phase 3: all 4 waves redundantly compute per-pixel top-8 (lane = pixel) by
//          (z asc, point-idx asc) — order-independent of the nondeterministic
//          LDS compaction order, and exactly reproduces top_k's tie-break.
// Phase 4: weights alpha = 1 - sqrt(clamp(d2/r^2, .001, 1)), front-to-back
//          transmittance; each wave composites a disjoint 16-channel slice
//          from LDS feature rows; coalesced stores over lanes (w).
// ---------------------------------------------------------------------------
__global__ __launch_bounds__(256) void raster_fused(
    const float* __restrict__ pts,   // [B, P, 3]
    const float* __restrict__ src,   // [B, C, P]
    float* __restrict__ out) {       // [B, C, H, W]
  __shared__ float4 cand[CAP];         // (x, y, z, idx_bits)
  __shared__ float feat[CAP * FPITCH]; // candidate feature rows, padded
  __shared__ int cnt_s;

  const int bid = blockIdx.x;
  const int b = bid >> 8;             // 256 blocks per batch
  const int h = (bid >> 1) & 127;
  const int w0 = (bid & 1) << 6;
  const int tid = threadIdx.x;

  if (tid == 0) cnt_s = 0;
  __syncthreads();

  const float r_ndc = 0.0234375f;     // RADIUS/SIZE*2 = 3/128, exact
  const float r2 = r_ndc * r_ndc;     // exact: 9*2^-14
  const float yc = 1.0f - 2.0f * (h + 0.5f) / 128.0f;

  // --- Phase 1: y-band scan into LDS candidate list ---
  const float* pb = pts + b * NPTS * 3;
  for (int p = tid; p < NPTS; p += 256) {
    float y = pb[p * 3 + 1];
    float dy = yc + y;                 // == yc - (-y), reference's dy
    if (dy * dy <= r2) {
      int pos = atomicAdd(&cnt_s, 1);  // ~48 hits/block: cheap
      if (pos < CAP)
        cand[pos] = make_float4(pb[p * 3 + 0], y, pb[p * 3 + 2],
                                __int_as_float(p));
    }
  }
  __syncthreads();
  const int cnt = min(cnt_s, CAP);

  // --- Phase 2: gather-transpose candidate feature rows into LDS ---
  // thread t -> (j = t/64, c = t%64); wave reads one row's 64 channels
  // (stride-P scatter, L2-hit); LDS write banks fully spread (2-way, free).
  const float* sbase = src + b * NCH * NPTS;
  for (int t = tid; t < cnt * NCH; t += 256) {
    int j = t >> 6;
    int c = t & 63;
    int p = __float_as_int(cand[j].w);
    feat[j * FPITCH + c] = sbase[c * NPTS + p];
  }
  if (cnt == 0 && tid < NCH) feat[tid] = 0.0f;  // avoid 0*NaN from stale LDS
  __syncthreads();

  const int pix = tid & 63;
  const int w = w0 + pix;
  const float xc = 1.0f - 2.0f * (w + 0.5f) / 128.0f;

  // --- Phase 3: top-8 by (z asc, point-idx asc); track LDS slot j ---
  float bz[KTOP], bd[KTOP];
  int bi[KTOP], bj[KTOP];
  #pragma unroll
  for (int k = 0; k < KTOP; ++k) {
    bz[k] = BIGF; bd[k] = 0.f; bi[k] = 0x7fffffff; bj[k] = 0;
  }

  for (int j = 0; j < cnt; ++j) {
    float4 c4 = cand[j];               // LDS broadcast (same addr all lanes)
    float dx = xc + c4.x;
    float dyy = yc + c4.y;
    float d2 = dx * dx + dyy * dyy;
    if (d2 <= r2) {
      float cz = c4.z, cd = d2;
      int ci = __float_as_int(c4.w);
      int cj = j;
      #pragma unroll
      for (int s = 0; s < KTOP; ++s) {
        bool lt = (cz < bz[s]) || (cz == bz[s] && ci < bi[s]);
        float tz = bz[s], td = bd[s];
        int ti = bi[s], tj = bj[s];
        if (lt) {
          bz[s] = cz; bd[s] = cd; bi[s] = ci; bj[s] = cj;
          cz = tz; cd = td; ci = ti; cj = tj;
        }
      }
    }
  }

  // --- Phase 4a: weights ---
  float wgt[KTOP];
  float T = 1.0f;
  const float inv_r2 = 1.0f / r2;
  #pragma unroll
  for (int k = 0; k < KTOP; ++k) {
    float alpha = 0.0f;
    if (bz[k] < BIGF) {
      float dist = bd[k] * inv_r2;
      dist = fminf(fmaxf(dist, 0.001f), 1.0f);
      alpha = 1.0f - sqrtf(dist);
    }
    wgt[k] = alpha * T;                // invalid slots: bj=0 (finite), wgt=0
    T *= (1.0f - alpha);
  }

  // --- Phase 4b: composite this wave's 16-channel slice from LDS rows ---
  const int cq0 = (tid >> 6) * 4;      // wave's float4-quad range
  const float4* frows[KTOP];
  #pragma unroll
  for (int k = 0; k < KTOP; ++k)
    frows[k] = (const float4*)&feat[bj[k] * FPITCH + cq0 * 4];

  float* ob = out + (b * NCH * IMG + h) * IMG + w;
  #pragma unroll
  for (int q = 0; q < 4; ++q) {
    float4 acc = {0.f, 0.f, 0.f, 0.f};
    #pragma unroll
    for (int k = 0; k < KTOP; ++k) {
      float4 v = frows[k][q];          // ds_read_b128, banks spread by j
      acc.x += wgt[k] * v.x;
      acc.y += wgt[k] * v.y;
      acc.z += wgt[k] * v.z;
      acc.w += wgt[k] * v.w;
    }
    int c = (cq0 + q) * 4;
    ob[(c + 0) * (IMG * IMG)] = acc.x;  // coalesced over lanes (w)
    ob[(c + 1) * (IMG * IMG)] = acc.y;
    ob[(c + 2) * (IMG * IMG)] = acc.z;
    ob[(c + 3) * (IMG * IMG)] = acc.w;
  }
}

extern "C" void kernel_launch(void* const* d_in, const int* in_sizes, int n_in,
                              void* d_out, int out_size, void* d_ws, size_t ws_size,
                              hipStream_t stream) {
  const float* pts = (const float*)d_in[0];   // [B,P,3]
  const float* src = (const float*)d_in[1];   // [B,C,P]
  float* out = (float*)d_out;                 // [B,C,H,W]

  raster_fused<<<BATCH * IMG * 2, 256, 0, stream>>>(pts, src, out);
}

// Round 5
// 86.025 us; speedup vs baseline: 1.0776x; 1.0776x over previous
//
#include <hip/hip_runtime.h>
#include <hip/hip_bf16.h>

// Problem constants
#define BATCH 2
#define NPTS 2048
#define NCH 64
#define IMG 128
#define KTOP 8
#define BIGF 1e10f
#define CAP 128   // per-row candidate capacity (expected ~48, CAP=128 passed R2-R4)

// ---------------------------------------------------------------------------
// Kernel 1: fused prep. blocks [0,64): transpose src [B,C,P] -> srcT [B,P,C].
// blocks [64,128): per-row binning, one wave per (b,h) row, ballot-compacted
// (deterministic, atomic-free, no memset; list sorted by point index, which
// makes a stable z-insertion reproduce top_k's lowest-index tie-break).
// ---------------------------------------------------------------------------
__global__ __launch_bounds__(256) void prep(
    const float* __restrict__ pts,   // [B, P, 3]
    const float* __restrict__ src,   // [B, C, P]
    float* __restrict__ srcT,        // [B, P, C]
    float4* __restrict__ bins,       // [B*IMG, CAP] (x, y, z, idx_bits)
    int* __restrict__ counts) {      // [B*IMG]
  const int blk = blockIdx.x;
  if (blk < 64) {
    // --- transpose ---
    __shared__ float tile[64][65];  // +1 pad: conflict-free
    int b = blk >> 5;
    int p0 = (blk & 31) << 6;
    int tx = threadIdx.x & 63;
    int ty = threadIdx.x >> 6;
    const float* s = src + b * NCH * NPTS;
    #pragma unroll
    for (int cc = 0; cc < 64; cc += 4) {
      int c = cc + ty;
      tile[tx][c] = s[c * NPTS + p0 + tx];  // coalesced over tx
    }
    __syncthreads();
    float* dT = srcT + (b * NPTS + p0) * NCH;
    #pragma unroll
    for (int pp = 0; pp < 64; pp += 4) {
      int p = pp + ty;
      dT[p * NCH + tx] = tile[p][tx];       // coalesced over tx
    }
  } else {
    // --- binning: wave handles row = (blk-64)*4 + waveid ---
    const int wave = threadIdx.x >> 6;
    const int lane = threadIdx.x & 63;
    const int row = ((blk - 64) << 2) + wave;   // 0..255 = b*IMG + h
    const int b = row >> 7;
    const int h = row & 127;
    const float r_ndc = 0.0234375f;             // 3/128 exact
    const float r2 = r_ndc * r_ndc;
    const float yc = 1.0f - 2.0f * (h + 0.5f) / 128.0f;
    const float* pb = pts + b * NPTS * 3;
    float4* brow = bins + row * CAP;
    int base = 0;
    for (int it = 0; it < NPTS / 64; ++it) {    // 32 iterations
      int p = (it << 6) + lane;
      float y = pb[p * 3 + 1];
      float dy = yc + y;                        // reference's dy, bit-exact
      bool hit = (dy * dy <= r2);               // conservative superset of
                                                // dx^2+dy^2<=r2 (fp-safe)
      unsigned long long mask = __ballot(hit);
      int prefix = __popcll(mask & ((1ull << lane) - 1ull));
      if (hit) {
        int pos = base + prefix;
        if (pos < CAP)
          brow[pos] = make_float4(pb[p * 3 + 0], y, pb[p * 3 + 2],
                                  __int_as_float(p));
      }
      base += __popcll(mask);
    }
    if (lane == 0) counts[row] = min(base, CAP);
  }
}

// ---------------------------------------------------------------------------
// Kernel 2: raster + composite. Grid = B*IMG*2*4 = 4096 blocks x 64 threads
// (1 wave, 2 KB LDS -> high co-residency, no cross-wave barriers).
// Wave = (batch, row, half, 16-channel group); lane = pixel.
// ---------------------------------------------------------------------------
__global__ __launch_bounds__(64) void raster(
    const float4* __restrict__ bins,  // [B*IMG, CAP]
    const int* __restrict__ counts,   // [B*IMG]
    const float* __restrict__ srcT,   // [B, P, C]
    float* __restrict__ out) {        // [B, C, H, W]
  __shared__ float4 cand[CAP];

  const int bid = blockIdx.x;
  const int cg = bid & 3;             // 16-channel group
  const int half = (bid >> 2) & 1;
  const int h = (bid >> 3) & 127;
  const int b = bid >> 10;
  const int lane = threadIdx.x;

  const int row = (b << 7) + h;
  const int cnt = min(counts[row], CAP);
  const float4* grow = bins + row * CAP;
  for (int j = lane; j < cnt; j += 64) cand[j] = grow[j];  // coalesced
  __syncthreads();                     // single wave: just a waitcnt

  const float r_ndc = 0.0234375f;
  const float r2 = r_ndc * r_ndc;
  const float yc = 1.0f - 2.0f * (h + 0.5f) / 128.0f;
  const int w = (half << 6) + lane;
  const float xc = 1.0f - 2.0f * (w + 0.5f) / 128.0f;

  // --- top-8 by z asc; list is p-sorted so stable strict < == top_k order ---
  float bz[KTOP], bd[KTOP];
  int bp[KTOP];
  #pragma unroll
  for (int k = 0; k < KTOP; ++k) { bz[k] = BIGF; bd[k] = 0.f; bp[k] = 0; }

  for (int j = 0; j < cnt; ++j) {
    float4 c4 = cand[j];               // LDS broadcast
    float dx = xc + c4.x;              // == xc - (-x), reference's dx
    float dyy = yc + c4.y;
    float d2 = dx * dx + dyy * dyy;
    if (d2 <= r2) {                    // rare per lane (~1 hit/pixel avg)
      float cz = c4.z, cd = d2;
      int cp = __float_as_int(c4.w);
      #pragma unroll
      for (int s = 0; s < KTOP; ++s) {
        bool lt = (cz < bz[s]);        // strict: stability = index tie-break
        float tz = bz[s], td = bd[s];
        int tp = bp[s];
        if (lt) { bz[s] = cz; bd[s] = cd; bp[s] = cp;
                  cz = tz; cd = td; cp = tp; }
      }
    }
  }

  // --- weights: alpha = 1 - sqrt(clamp(d2/r^2, .001, 1)); front-to-back ---
  float wgt[KTOP];
  float T = 1.0f;
  const float inv_r2 = 1.0f / r2;
  #pragma unroll
  for (int k = 0; k < KTOP; ++k) {
    float alpha = 0.0f;
    if (bz[k] < BIGF) {
      float dist = bd[k] * inv_r2;
      dist = fminf(fmaxf(dist, 0.001f), 1.0f);
      alpha = 1.0f - sqrtf(dist);
    }
    wgt[k] = alpha * T;                // unfilled: bp=0 (safe row), wgt=0
    T *= (1.0f - alpha);
  }

  // --- composite this wave's 16 channels from srcT (L2-hit gathers) ---
  const float* sb = srcT + (size_t)b * NPTS * NCH + cg * 16;
  float4 acc0 = {0,0,0,0}, acc1 = {0,0,0,0}, acc2 = {0,0,0,0}, acc3 = {0,0,0,0};
  #pragma unroll
  for (int k = 0; k < KTOP; ++k) {
    const float4* fr = (const float4*)(sb + (size_t)bp[k] * NCH);
    float wk = wgt[k];
    float4 v0 = fr[0], v1 = fr[1], v2 = fr[2], v3 = fr[3];
    acc0.x += wk * v0.x; acc0.y += wk * v0.y; acc0.z += wk * v0.z; acc0.w += wk * v0.w;
    acc1.x += wk * v1.x; acc1.y += wk * v1.y; acc1.z += wk * v1.z; acc1.w += wk * v1.w;
    acc2.x += wk * v2.x; acc2.y += wk * v2.y; acc2.z += wk * v2.z; acc2.w += wk * v2.w;
    acc3.x += wk * v3.x; acc3.y += wk * v3.y; acc3.z += wk * v3.z; acc3.w += wk * v3.w;
  }

  float* ob = out + (((size_t)b * NCH + cg * 16) * IMG + h) * IMG + w;
  const int S = IMG * IMG;
  ob[0 * S] = acc0.x;  ob[1 * S] = acc0.y;  ob[2 * S] = acc0.z;  ob[3 * S] = acc0.w;
  ob[4 * S] = acc1.x;  ob[5 * S] = acc1.y;  ob[6 * S] = acc1.z;  ob[7 * S] = acc1.w;
  ob[8 * S] = acc2.x;  ob[9 * S] = acc2.y;  ob[10 * S] = acc2.z; ob[11 * S] = acc2.w;
  ob[12 * S] = acc3.x; ob[13 * S] = acc3.y; ob[14 * S] = acc3.z; ob[15 * S] = acc3.w;
}

extern "C" void kernel_launch(void* const* d_in, const int* in_sizes, int n_in,
                              void* d_out, int out_size, void* d_ws, size_t ws_size,
                              hipStream_t stream) {
  const float* pts = (const float*)d_in[0];   // [B,P,3]
  const float* src = (const float*)d_in[1];   // [B,C,P]
  float* out = (float*)d_out;                 // [B,C,H,W]

  // ws layout: srcT (1 MB) | bins (512 KB) | counts (1 KB)
  char* ws = (char*)d_ws;
  float* srcT = (float*)ws;
  float4* bins = (float4*)(ws + (size_t)BATCH * NPTS * NCH * 4);
  int* counts = (int*)(ws + (size_t)BATCH * NPTS * NCH * 4 +
                       (size_t)BATCH * IMG * CAP * 16);

  prep<<<128, 256, 0, stream>>>(pts, src, srcT, bins, counts);
  raster<<<BATCH * IMG * 2 * 4, 64, 0, stream>>>(bins, counts, srcT, out);
}

// Round 6
// 83.552 us; speedup vs baseline: 1.1094x; 1.0296x over previous
//
#include <hip/hip_runtime.h>
#include <hip/hip_bf16.h>

// Problem constants
#define BATCH 2
#define NPTS 2048
#define NCH 64
#define IMG 128
#define KTOP 8
#define BIGF 1e10f
#define CAP 128   // per-row candidate capacity (expected ~48; CAP=128 passed R2-R5)

// ---------------------------------------------------------------------------
// Single megakernel: scan + rasterize(top-8 z) + composite. No workspace.
// Grid = B*IMG*2*4 = 4096 blocks x 64 threads (1 wave, 2 KB LDS -> high
// co-residency, no cross-wave barriers). Wave = (batch, row, half, 16-channel
// group); lane = pixel.
//
// Phase 1: ballot-compacted y-band scan of all 2048 points into LDS.
//          dy^2 <= r2 is a conservative superset of dx^2+dy^2 <= r2
//          (fl(a+b) >= b for a,b >= 0); dy computed bit-identically to the
//          reference (yc + y == yc - (-y)). Compaction preserves point-index
//          order, so a stable strict-z insertion reproduces top_k's
//          lowest-index tie-break.
// Phase 2: per-lane top-8 by z (stable insert), tracking d2 and point idx.
// Phase 3: alpha = 1 - sqrt(clamp(d2/r^2, .001, 1)), front-to-back
//          transmittance weights; composite 16 channels directly from
//          src [B,C,P] (scalar L1/L2-hit gathers; <=48 distinct points per
//          row shared across lanes); coalesced stores over lanes (w).
// ---------------------------------------------------------------------------
__global__ __launch_bounds__(64) void raster_mega(
    const float* __restrict__ pts,   // [B, P, 3]
    const float* __restrict__ src,   // [B, C, P]
    float* __restrict__ out) {       // [B, C, H, W]
  __shared__ float4 cand[CAP];       // (x, y, z, idx_bits), p-ordered

  const int bid = blockIdx.x;
  const int cg = bid & 3;            // 16-channel group
  const int half = (bid >> 2) & 1;
  const int h = (bid >> 3) & 127;
  const int b = bid >> 10;
  const int lane = threadIdx.x;

  const float r_ndc = 0.0234375f;    // RADIUS/SIZE*2 = 3/128, exact
  const float r2 = r_ndc * r_ndc;    // exact: 9*2^-14
  const float yc = 1.0f - 2.0f * (h + 0.5f) / 128.0f;

  // --- Phase 1: ballot-compacted scan into LDS (p-order preserved) ---
  const float* pb = pts + b * NPTS * 3;
  int base = 0;
  for (int it = 0; it < NPTS / 64; ++it) {   // 32 iterations
    int p = (it << 6) + lane;
    float y = pb[p * 3 + 1];                 // L1-hit (pts: 24 KB/batch)
    float dy = yc + y;                       // reference's dy, bit-exact
    bool hit = (dy * dy <= r2);
    unsigned long long mask = __ballot(hit);
    if (mask) {                              // wave-uniform branch
      if (hit) {
        int pos = base + __popcll(mask & ((1ull << lane) - 1ull));
        if (pos < CAP)
          cand[pos] = make_float4(pb[p * 3 + 0], y, pb[p * 3 + 2],
                                  __int_as_float(p));
      }
      base += __popcll(mask);
    }
  }
  __syncthreads();                           // 1 wave: just lgkmcnt drain
  const int cnt = min(base, CAP);

  const int w = (half << 6) + lane;
  const float xc = 1.0f - 2.0f * (w + 0.5f) / 128.0f;

  // --- Phase 2: top-8 by z asc; stable strict < == top_k order ---
  float bz[KTOP], bd[KTOP];
  int bp[KTOP];
  #pragma unroll
  for (int k = 0; k < KTOP; ++k) { bz[k] = BIGF; bd[k] = 0.f; bp[k] = 0; }

  for (int j = 0; j < cnt; ++j) {
    float4 c4 = cand[j];                     // LDS broadcast
    float dx = xc + c4.x;                    // == xc - (-x), reference's dx
    float dyy = yc + c4.y;
    float d2 = dx * dx + dyy * dyy;
    if (d2 <= r2) {                          // rare per lane (~0.9 hits avg)
      float cz = c4.z, cd = d2;
      int cp = __float_as_int(c4.w);
      #pragma unroll
      for (int s = 0; s < KTOP; ++s) {
        bool lt = (cz < bz[s]);              // strict: stability = tie-break
        float tz = bz[s], td = bd[s];
        int tp = bp[s];
        if (lt) { bz[s] = cz; bd[s] = cd; bp[s] = cp;
                  cz = tz; cd = td; cp = tp; }
      }
    }
  }

  // --- Phase 3a: weights ---
  float wgt[KTOP];
  float T = 1.0f;
  const float inv_r2 = 1.0f / r2;
  #pragma unroll
  for (int k = 0; k < KTOP; ++k) {
    float alpha = 0.0f;
    if (bz[k] < BIGF) {
      float dist = bd[k] * inv_r2;
      dist = fminf(fmaxf(dist, 0.001f), 1.0f);
      alpha = 1.0f - sqrtf(dist);
    }
    wgt[k] = alpha * T;                      // unfilled: bp=0 (safe), wgt=0
    T *= (1.0f - alpha);
  }

  // --- Phase 3b: composite 16 channels straight from src [B,C,P] ---
  const float* sb = src + ((size_t)b * NCH + cg * 16) * NPTS;
  float acc[16];
  #pragma unroll
  for (int c = 0; c < 16; ++c) acc[c] = 0.0f;
  #pragma unroll
  for (int k = 0; k < KTOP; ++k) {
    float wk = wgt[k];
    int p = bp[k];
    #pragma unroll
    for (int c = 0; c < 16; ++c)
      acc[c] += wk * sb[c * NPTS + p];       // L1/L2-hit scalar gathers
  }

  float* ob = out + (((size_t)b * NCH + cg * 16) * IMG + h) * IMG + w;
  const int S = IMG * IMG;
  #pragma unroll
  for (int c = 0; c < 16; ++c)
    ob[c * S] = acc[c];                      // coalesced over lanes (w)
}

extern "C" void kernel_launch(void* const* d_in, const int* in_sizes, int n_in,
                              void* d_out, int out_size, void* d_ws, size_t ws_size,
                              hipStream_t stream) {
  const float* pts = (const float*)d_in[0];   // [B,P,3]
  const float* src = (const float*)d_in[1];   // [B,C,P]
  float* out = (float*)d_out;                 // [B,C,H,W]

  raster_mega<<<BATCH * IMG * 2 * 4, 64, 0, stream>>>(pts, src, out);
}